// Round 1
// baseline (104.289 us; speedup 1.0000x reference)
//
#include <hip/hip_runtime.h>

// TT Q-gather v2 — pair-folded tables, bf16 storage.
//
//   v = V01[s0][s1][:]        (1 MB table)
//   v = v @ T23[s2][s3]       (8 MB table: folded G2*G3, 8x8 bf16/entry)
//   v = v @ T45[s4][s5]       (8 MB table: folded G4*G5)
//   q = v . U67[s6][a7][:]    (1 MB table: folded G6*G7)
//
// Rationale (R0 counters): timed region = 42us harness ws-fill (256MiB
// poison, uncontrollable) + ~60us kernels, gather-dominated. Gather cost
// scales with divergent lane-addresses/element: was 34 x 16B, now 18
// (-47%), and fp32 chain FMAs halve (512 -> 256). All 18 addresses are
// index-derived -> issued up-front for full MLP.
//
// ws layout (ushort units):
//   V01 @ 0        : [s0][s1][s] 256*256*8   (1 MB)
//   U67 @ 524288   : [s6][a7][r] 256*256*8   (1 MB)
//   T23 @ 1048576  : [s2][s3][r][s] 256*256*64 (8 MB)
//   T45 @ 5242880  : [s4][s5][r][s] 256*256*64 (8 MB)

#define NN 256
#define RR 8
#define NR 2048   // N * R
#define U67_OFF 524288
#define T23_OFF 1048576
#define T45_OFF 5242880

__device__ __forceinline__ unsigned short f2bf_rne(float f) {
    unsigned int u = __float_as_uint(f);
    u += 0x7FFFu + ((u >> 16) & 1u);
    return (unsigned short)(u >> 16);
}

__device__ __forceinline__ uint4 pack8bf(const float* a) {
    return make_uint4(
        f2bf_rne(a[0]) | ((unsigned int)f2bf_rne(a[1]) << 16),
        f2bf_rne(a[2]) | ((unsigned int)f2bf_rne(a[3]) << 16),
        f2bf_rne(a[4]) | ((unsigned int)f2bf_rne(a[5]) << 16),
        f2bf_rne(a[6]) | ((unsigned int)f2bf_rne(a[7]) << 16));
}

// 1024 blocks x 256 threads:
//   0..255    -> V01 row s0
//   256..511  -> U67 row s6
//   512..767  -> T23 slab n2 (all 256 n3 entries)
//   768..1023 -> T45 slab n4
__global__ __launch_bounds__(256) void build_tables(
    const float* __restrict__ G0, const float* __restrict__ G1,
    const float* __restrict__ G2, const float* __restrict__ G3,
    const float* __restrict__ G4, const float* __restrict__ G5,
    const float* __restrict__ G6, const float* __restrict__ G7,
    unsigned short* __restrict__ wsb) {
    __shared__ float Ash[64];
    const int t = threadIdx.x;
    const int bid = blockIdx.x;

    if (bid < NN) {
        // V01[n0][n1][s] = sum_r G0[n0,r] * G1[r,n1,s]
        const int n0 = bid, n1 = t;
        float acc[RR] = {0.f,0.f,0.f,0.f,0.f,0.f,0.f,0.f};
#pragma unroll
        for (int r = 0; r < RR; ++r) {
            float ar = G0[n0 * RR + r];
            const float4* p = (const float4*)(G1 + r * NR + n1 * RR);
            float4 x = p[0], y = p[1];
            acc[0] += ar * x.x; acc[1] += ar * x.y;
            acc[2] += ar * x.z; acc[3] += ar * x.w;
            acc[4] += ar * y.x; acc[5] += ar * y.y;
            acc[6] += ar * y.z; acc[7] += ar * y.w;
        }
        *(uint4*)(wsb + n0 * 2048 + n1 * 8) = pack8bf(acc);
    } else if (bid < 2 * NN) {
        // U67[n6][n7][r] = sum_s G6[r,n6,s] * G7[s,n7]
        const int n6 = bid - NN, n7 = t;
        float g7v[RR];
#pragma unroll
        for (int s = 0; s < RR; ++s) g7v[s] = G7[s * NN + n7];
        float u[RR];
#pragma unroll
        for (int r = 0; r < RR; ++r) {
            float acc = 0.f;
#pragma unroll
            for (int s = 0; s < RR; ++s)
                acc += G6[r * NR + n6 * RR + s] * g7v[s];
            u[r] = acc;
        }
        *(uint4*)(wsb + U67_OFF + n6 * 2048 + n7 * 8) = pack8bf(u);
    } else {
        // Pair tables: T[n2][n3][r][s] = sum_m A[r,n2,m] * B[m,n3,s]
        const int q = bid - 2 * NN;        // 0..511
        const int isT45 = q >> 8;          // 0 -> (G2,G3), 1 -> (G4,G5)
        const int n2 = q & 255;
        const float* __restrict__ A = isT45 ? G4 : G2;
        const float* __restrict__ Bm = isT45 ? G5 : G3;
        unsigned short* __restrict__ dst =
            wsb + (isT45 ? T45_OFF : T23_OFF);

        // stage A = A[:, n2, :] (8x8) into LDS, broadcast-read later
        if (t < 16) {
            const int r = t >> 1, h = t & 1;
            *(float4*)(Ash + r * 8 + h * 4) =
                *(const float4*)(A + r * NR + n2 * RR + h * 4);
        }
        __syncthreads();

        const int n3 = t;
        float acc[64];
#pragma unroll
        for (int i = 0; i < 64; ++i) acc[i] = 0.f;
#pragma unroll
        for (int m = 0; m < 8; ++m) {
            const float4* bp = (const float4*)(Bm + m * NR + n3 * RR);
            float4 b0 = bp[0], b1 = bp[1];
#pragma unroll
            for (int r = 0; r < 8; ++r) {
                float a = Ash[r * 8 + m];
                acc[r*8+0] += a * b0.x; acc[r*8+1] += a * b0.y;
                acc[r*8+2] += a * b0.z; acc[r*8+3] += a * b0.w;
                acc[r*8+4] += a * b1.x; acc[r*8+5] += a * b1.y;
                acc[r*8+6] += a * b1.z; acc[r*8+7] += a * b1.w;
            }
        }
        uint4* o = (uint4*)(dst + ((n2 << 8) + n3) * 64);
#pragma unroll
        for (int r = 0; r < 8; ++r) o[r] = pack8bf(acc + r * 8);
    }
}

#define BF2F_LO(u) __uint_as_float((u) << 16)
#define BF2F_HI(u) __uint_as_float((u) & 0xFFFF0000u)

__global__ __launch_bounds__(256) void tt_gather(
    const unsigned short* __restrict__ wsb,
    const int* __restrict__ states, const int* __restrict__ actions,
    float* __restrict__ out, int B) {
    __shared__ int ibuf[NN * 7];   // 7 KB: this block's 256 state rows

    const int t = threadIdx.x;
    const int b = blockIdx.x * 256 + t;

    // coalesced staging of states rows
    {
        const int* gsrc = states + (size_t)blockIdx.x * 256 * 7;
        const int lim = B * 7 - blockIdx.x * 256 * 7;
#pragma unroll
        for (int k = 0; k < 7; ++k) {
            int j = t + (k << 8);
            if (j < lim) ibuf[j] = gsrc[j];
        }
    }
    __syncthreads();

    const bool active = (b < B);
    const int* row = ibuf + t * 7;            // stride 7: conflict-free
    const int s0 = row[0] & 255;
    const int s1 = row[1] & 255;
    const int s2 = row[2] & 255;
    const int s3 = row[3] & 255;
    const int s4 = row[4] & 255;
    const int s5 = row[5] & 255;
    const int s6 = row[6] & 255;
    const int a7 = actions[active ? b : 0] & 255;

    // all 18 gather addresses are index-derived: issue everything up front
    const uint4* p01 = (const uint4*)(wsb + s0 * 2048 + s1 * 8);
    const uint4* p23 = (const uint4*)(wsb + T23_OFF + ((s2 << 8) + s3) * 64);
    const uint4* p45 = (const uint4*)(wsb + T45_OFF + ((s4 << 8) + s5) * 64);
    const uint4* p67 = (const uint4*)(wsb + U67_OFF + s6 * 2048 + a7 * 8);

    uint4 uv = *p01;
    uint4 m[8], w[8];
#pragma unroll
    for (int r = 0; r < 8; ++r) m[r] = p23[r];
#pragma unroll
    for (int r = 0; r < 8; ++r) w[r] = p45[r];
    uint4 ue = *p67;

    float v[8];
    v[0] = BF2F_LO(uv.x); v[1] = BF2F_HI(uv.x);
    v[2] = BF2F_LO(uv.y); v[3] = BF2F_HI(uv.y);
    v[4] = BF2F_LO(uv.z); v[5] = BF2F_HI(uv.z);
    v[6] = BF2F_LO(uv.w); v[7] = BF2F_HI(uv.w);

    float nv[8];
#pragma unroll
    for (int i = 0; i < 8; ++i) nv[i] = 0.f;
#pragma unroll
    for (int r = 0; r < 8; ++r) {
        float vr = v[r];
        nv[0] += vr * BF2F_LO(m[r].x); nv[1] += vr * BF2F_HI(m[r].x);
        nv[2] += vr * BF2F_LO(m[r].y); nv[3] += vr * BF2F_HI(m[r].y);
        nv[4] += vr * BF2F_LO(m[r].z); nv[5] += vr * BF2F_HI(m[r].z);
        nv[6] += vr * BF2F_LO(m[r].w); nv[7] += vr * BF2F_HI(m[r].w);
    }

    float fv[8];
#pragma unroll
    for (int i = 0; i < 8; ++i) fv[i] = 0.f;
#pragma unroll
    for (int r = 0; r < 8; ++r) {
        float vr = nv[r];
        fv[0] += vr * BF2F_LO(w[r].x); fv[1] += vr * BF2F_HI(w[r].x);
        fv[2] += vr * BF2F_LO(w[r].y); fv[3] += vr * BF2F_HI(w[r].y);
        fv[4] += vr * BF2F_LO(w[r].z); fv[5] += vr * BF2F_HI(w[r].z);
        fv[6] += vr * BF2F_LO(w[r].w); fv[7] += vr * BF2F_HI(w[r].w);
    }

    float q = fv[0] * BF2F_LO(ue.x) + fv[1] * BF2F_HI(ue.x)
            + fv[2] * BF2F_LO(ue.y) + fv[3] * BF2F_HI(ue.y)
            + fv[4] * BF2F_LO(ue.z) + fv[5] * BF2F_HI(ue.z)
            + fv[6] * BF2F_LO(ue.w) + fv[7] * BF2F_HI(ue.w);
    if (active) out[b] = q;
}

extern "C" void kernel_launch(void* const* d_in, const int* in_sizes, int n_in,
                              void* d_out, int out_size, void* d_ws, size_t ws_size,
                              hipStream_t stream) {
    const float* G0 = (const float*)d_in[0];
    const float* G1 = (const float*)d_in[1];
    const float* G2 = (const float*)d_in[2];
    const float* G3 = (const float*)d_in[3];
    const float* G4 = (const float*)d_in[4];
    const float* G5 = (const float*)d_in[5];
    const float* G6 = (const float*)d_in[6];
    const float* G7 = (const float*)d_in[7];
    const int* states  = (const int*)d_in[8];
    const int* actions = (const int*)d_in[9];
    float* out = (float*)d_out;
    int B = in_sizes[9];

    unsigned short* wsb = (unsigned short*)d_ws;   // 18 MB used

    hipLaunchKernelGGL(build_tables, dim3(2 * NN + 512), dim3(256), 0, stream,
                       G0, G1, G2, G3, G4, G5, G6, G7, wsb);

    hipLaunchKernelGGL(tt_gather, dim3((B + 255) / 256), dim3(256), 0, stream,
                       wsb, states, actions, out, B);
}